// Round 1
// baseline (166.062 us; speedup 1.0000x reference)
//
#include <hip/hip_runtime.h>
#include <hip/hip_bf16.h>

// SLAY features: B=8192, EMBED=1024, H=16, D=64, M=32, P=16, R=2
// out[b, r*8192 + h*512 + p*32 + m] = poly_feat[b,h,p] * prf_feat[r,b,h,m]
//
// One wave handles (h, b0, b0+1). Memory-bound on the 512 MiB f32 output.

#define NUM_H 16
#define DIM 64
#define NUM_M 32
#define NUM_P 16
#define PM 512            // P*M
#define ROWLEN 16384      // R*H*PM

__global__ __launch_bounds__(256) void slay_features_kernel(
    const float* __restrict__ x,
    const float* __restrict__ omega,
    const float* __restrict__ anchors,
    float* __restrict__ out)
{
    __shared__ float  shA[DIM * NUM_P];   // anchors transposed: [d][p] (conflict-free reads)
    __shared__ float2 shXn[4][DIM];       // per-wave normalized x for (b0, b1)

    const int tid  = threadIdx.x;
    const int lane = tid & 63;
    const int wv   = tid >> 6;
    const int h    = blockIdx.y;

    // stage anchors [p][d] -> LDS [d][p] (coalesced global read; one-time scatter write)
    for (int e = tid; e < NUM_P * DIM; e += 256) {
        const int p = e >> 6;
        const int d = e & 63;
        shA[d * NUM_P + p] = anchors[e];
    }

    const int bp = blockIdx.x * 4 + wv;   // b-pair index
    const int b0 = bp * 2;

    // ---- load + normalize two x rows (64 floats each, one per lane) ----
    const float xa = x[(size_t)b0 * 1024 + h * 64 + lane];
    const float xb = x[(size_t)(b0 + 1) * 1024 + h * 64 + lane];
    float sa = xa * xa, sb = xb * xb;
    #pragma unroll
    for (int o = 32; o > 0; o >>= 1) {
        sa += __shfl_xor(sa, o);
        sb += __shfl_xor(sb, o);
    }
    const float xna = xa / (sqrtf(fmaxf(sa, 1e-12f)) + 1e-4f);
    const float xnb = xb / (sqrtf(fmaxf(sb, 1e-12f)) + 1e-4f);
    shXn[wv][lane] = make_float2(xna, xnb);
    __syncthreads();

    // ---- dot products over d ----
    // lane computes: prf proj for (r = lane>>5, m = lane&31), poly proj for p = lane&15
    const float* og = omega + (size_t)(lane >> 5) * 32768 + (size_t)h * 2048 + (lane & 31);
    const float* ap = shA + (lane & 15);
    const float2* xp = shXn[wv];

    float pr0 = 0.f, pr1 = 0.f, pl0 = 0.f, pl1 = 0.f;
    #pragma unroll
    for (int d = 0; d < DIM; ++d) {
        const float2 xn = xp[d];               // uniform addr -> broadcast
        const float  w  = og[(size_t)d * 32];  // L1-resident omega slice
        const float  a  = ap[d * NUM_P];       // 16 banks x 4-lane broadcast
        pr0 = fmaf(xn.x, w, pr0);
        pr1 = fmaf(xn.y, w, pr1);
        pl0 = fmaf(xn.x, a, pl0);
        pl1 = fmaf(xn.y, a, pl1);
    }

    // ---- quadrature constants (match ref: float32(node) / C, then f32 math) ----
    const float S0 = (float)(0.5857864376269049 / 2.000001);
    const float S1 = (float)(3.4142135623730951 / 2.000001);
    const float Q0 = sqrtf(2.0f * S0);
    const float Q1 = sqrtf(2.0f * S1);
    const float K0 = sqrtf((float)(0.8535533905932737  / 2.000001) / 32.0f); // sqrt(w0/C)/sqrt(32)
    const float K1 = sqrtf((float)(0.14644660940672624 / 2.000001) / 32.0f);
    const bool  hi = lane >= 32;
    const float sR = hi ? S1 : S0;
    const float qR = hi ? Q1 : Q0;
    const float kR = hi ? K1 : K0;

    // epilogue gather indices: lane writes float4 at idx = c*256 + lane*4 within a 512 block
    // p = c*8 + (lane>>3), m = (lane&7)*4 + j
    const int mb = (lane & 7) * 4;
    const int ps = lane >> 3;

    float* ob = out + (size_t)b0 * ROWLEN + h * PM;

    #pragma unroll
    for (int bb = 0; bb < 2; ++bb) {
        const float pr = bb ? pr1 : pr0;
        const float pl = bb ? pl1 : pl0;

        float arg = fmaf(pr, qR, -sR);
        arg = fminf(fmaxf(arg, -20.f), 20.f);
        const float prf = __expf(arg) * kR;      // lane's prf_feat(r=lane>>5, m=lane&31)
        const float pf  = pl * pl * 0.25f;       // lane's poly_feat(p=lane&15)

        const float p0  = __shfl(pf, ps);        // poly for c=0 chunk
        const float p1  = __shfl(pf, 8 + ps);    // poly for c=1 chunk
        const float q00 = __shfl(prf, mb + 0);   // r=0, m=mb..mb+3
        const float q01 = __shfl(prf, mb + 1);
        const float q02 = __shfl(prf, mb + 2);
        const float q03 = __shfl(prf, mb + 3);
        const float q10 = __shfl(prf, 32 + mb + 0); // r=1
        const float q11 = __shfl(prf, 32 + mb + 1);
        const float q12 = __shfl(prf, 32 + mb + 2);
        const float q13 = __shfl(prf, 32 + mb + 3);

        float* o = ob + (size_t)bb * ROWLEN;
        *(float4*)(o + lane * 4)              = make_float4(p0*q00, p0*q01, p0*q02, p0*q03); // r0,c0
        *(float4*)(o + 256 + lane * 4)        = make_float4(p1*q00, p1*q01, p1*q02, p1*q03); // r0,c1
        *(float4*)(o + 8192 + lane * 4)       = make_float4(p0*q10, p0*q11, p0*q12, p0*q13); // r1,c0
        *(float4*)(o + 8192 + 256 + lane * 4) = make_float4(p1*q10, p1*q11, p1*q12, p1*q13); // r1,c1
    }
}

extern "C" void kernel_launch(void* const* d_in, const int* in_sizes, int n_in,
                              void* d_out, int out_size, void* d_ws, size_t ws_size,
                              hipStream_t stream) {
    const float* x       = (const float*)d_in[0];
    const float* omega   = (const float*)d_in[1];
    const float* anchors = (const float*)d_in[2];
    float* out = (float*)d_out;

    const int B = in_sizes[0] / 1024;       // 8192
    dim3 grid(B / 8, NUM_H);                // 4 waves/block, 2 b's per wave
    dim3 block(256);
    slay_features_kernel<<<grid, block, 0, stream>>>(x, omega, anchors, out);
}

// Round 2
// 141.268 us; speedup vs baseline: 1.1755x; 1.1755x over previous
//
#include <hip/hip_runtime.h>
#include <hip/hip_bf16.h>

// SLAY features: B=8192, EMBED=1024, H=16, D=64, M=32, P=16, R=2
// out[b, r*8192 + h*512 + p*32 + m] = poly_feat[b,h,p] * prf_feat[r,b,h,m]
//
// One wave handles (h, b0, b0+1). Memory-bound on the 512 MiB f32 output.
// Grid is FLAT with h in the low 4 bits so that concurrently-resident blocks
// cover all h for adjacent b-rows -> dense sequential coverage of the output
// address space (HBM channel balance), instead of 2KB-every-64KB strides.

#define NUM_H 16
#define DIM 64
#define NUM_M 32
#define NUM_P 16
#define PM 512            // P*M
#define ROWLEN 16384      // R*H*PM

__global__ __launch_bounds__(256) void slay_features_kernel(
    const float* __restrict__ x,
    const float* __restrict__ omega,
    const float* __restrict__ anchors,
    float* __restrict__ out)
{
    __shared__ float  shA[DIM * NUM_P];   // anchors transposed: [d][p] (conflict-free reads)
    __shared__ float2 shXn[4][DIM];       // per-wave normalized x for (b0, b1)

    const int tid  = threadIdx.x;
    const int lane = tid & 63;
    const int wv   = tid >> 6;
    const int h    = blockIdx.x & 15;     // low bits: all h adjacent in dispatch order
    const int bg   = blockIdx.x >> 4;     // b-group of 8 rows

    // stage anchors [p][d] -> LDS [d][p] (coalesced global read; one-time scatter write)
    for (int e = tid; e < NUM_P * DIM; e += 256) {
        const int p = e >> 6;
        const int d = e & 63;
        shA[d * NUM_P + p] = anchors[e];
    }

    const int b0 = bg * 8 + wv * 2;

    // ---- load + normalize two x rows (64 floats each, one per lane) ----
    const float xa = x[(size_t)b0 * 1024 + h * 64 + lane];
    const float xb = x[(size_t)(b0 + 1) * 1024 + h * 64 + lane];
    float sa = xa * xa, sb = xb * xb;
    #pragma unroll
    for (int o = 32; o > 0; o >>= 1) {
        sa += __shfl_xor(sa, o);
        sb += __shfl_xor(sb, o);
    }
    const float xna = xa / (sqrtf(fmaxf(sa, 1e-12f)) + 1e-4f);
    const float xnb = xb / (sqrtf(fmaxf(sb, 1e-12f)) + 1e-4f);
    shXn[wv][lane] = make_float2(xna, xnb);
    __syncthreads();

    // ---- dot products over d ----
    // lane computes: prf proj for (r = lane>>5, m = lane&31), poly proj for p = lane&15
    const float* og = omega + (size_t)(lane >> 5) * 32768 + (size_t)h * 2048 + (lane & 31);
    const float* ap = shA + (lane & 15);
    const float2* xp = shXn[wv];

    float pr0 = 0.f, pr1 = 0.f, pl0 = 0.f, pl1 = 0.f;
    #pragma unroll
    for (int d = 0; d < DIM; ++d) {
        const float2 xn = xp[d];               // uniform addr -> broadcast
        const float  w  = og[(size_t)d * 32];  // L2-resident omega slice
        const float  a  = ap[d * NUM_P];       // 16 banks x 4-lane broadcast
        pr0 = fmaf(xn.x, w, pr0);
        pr1 = fmaf(xn.y, w, pr1);
        pl0 = fmaf(xn.x, a, pl0);
        pl1 = fmaf(xn.y, a, pl1);
    }

    // ---- quadrature constants (match ref: float32(node) / C, then f32 math) ----
    const float S0 = (float)(0.5857864376269049 / 2.000001);
    const float S1 = (float)(3.4142135623730951 / 2.000001);
    const float Q0 = sqrtf(2.0f * S0);
    const float Q1 = sqrtf(2.0f * S1);
    const float K0 = sqrtf((float)(0.8535533905932737  / 2.000001) / 32.0f); // sqrt(w0/C)/sqrt(32)
    const float K1 = sqrtf((float)(0.14644660940672624 / 2.000001) / 32.0f);
    const bool  hi = lane >= 32;
    const float sR = hi ? S1 : S0;
    const float qR = hi ? Q1 : Q0;
    const float kR = hi ? K1 : K0;

    // epilogue gather indices: lane writes float4 at idx = c*256 + lane*4 within a 512 block
    // p = c*8 + (lane>>3), m = (lane&7)*4 + j
    const int mb = (lane & 7) * 4;
    const int ps = lane >> 3;

    float* ob = out + (size_t)b0 * ROWLEN + h * PM;

    #pragma unroll
    for (int bb = 0; bb < 2; ++bb) {
        const float pr = bb ? pr1 : pr0;
        const float pl = bb ? pl1 : pl0;

        float arg = fmaf(pr, qR, -sR);
        arg = fminf(fmaxf(arg, -20.f), 20.f);
        const float prf = __expf(arg) * kR;      // lane's prf_feat(r=lane>>5, m=lane&31)
        const float pf  = pl * pl * 0.25f;       // lane's poly_feat(p=lane&15)

        const float p0  = __shfl(pf, ps);        // poly for c=0 chunk
        const float p1  = __shfl(pf, 8 + ps);    // poly for c=1 chunk
        const float q00 = __shfl(prf, mb + 0);   // r=0, m=mb..mb+3
        const float q01 = __shfl(prf, mb + 1);
        const float q02 = __shfl(prf, mb + 2);
        const float q03 = __shfl(prf, mb + 3);
        const float q10 = __shfl(prf, 32 + mb + 0); // r=1
        const float q11 = __shfl(prf, 32 + mb + 1);
        const float q12 = __shfl(prf, 32 + mb + 2);
        const float q13 = __shfl(prf, 32 + mb + 3);

        float* o = ob + (size_t)bb * ROWLEN;
        *(float4*)(o + lane * 4)              = make_float4(p0*q00, p0*q01, p0*q02, p0*q03); // r0,c0
        *(float4*)(o + 256 + lane * 4)        = make_float4(p1*q00, p1*q01, p1*q02, p1*q03); // r0,c1
        *(float4*)(o + 8192 + lane * 4)       = make_float4(p0*q10, p0*q11, p0*q12, p0*q13); // r1,c0
        *(float4*)(o + 8192 + 256 + lane * 4) = make_float4(p1*q10, p1*q11, p1*q12, p1*q13); // r1,c1
    }
}

extern "C" void kernel_launch(void* const* d_in, const int* in_sizes, int n_in,
                              void* d_out, int out_size, void* d_ws, size_t ws_size,
                              hipStream_t stream) {
    const float* x       = (const float*)d_in[0];
    const float* omega   = (const float*)d_in[1];
    const float* anchors = (const float*)d_in[2];
    float* out = (float*)d_out;

    const int B = in_sizes[0] / 1024;       // 8192
    dim3 grid((B / 8) * NUM_H);             // flat: h = bid & 15, b-group = bid >> 4
    dim3 block(256);
    slay_features_kernel<<<grid, block, 0, stream>>>(x, omega, anchors, out);
}

// Round 3
// 114.146 us; speedup vs baseline: 1.4548x; 1.2376x over previous
//
#include <hip/hip_runtime.h>
#include <hip/hip_bf16.h>

// SLAY features: B=8192, EMBED=1024, H=16, D=64, M=32, P=16, R=2
// out[b, r*8192 + h*512 + p*32 + m] = poly_feat[b,h,p] * prf_feat[r,b,h,m]
//
// One wave handles (h, b0, b0+1).
// Key change vs R1: no x-transpose through LDS. Normalization commutes with
// the dot product (dot(xn,w) = dot(x,w)*inv_norm), so each lane reads the x
// row via wave-uniform scalar float4 loads and computes sumsq inline. Anchors
// are read as ds_read_b128 from a padded [16][68] LDS tile (2-way conflict =
// free). DS-pipe cycles/wave drop ~1070 -> ~310, below the HBM write floor.

#define NUM_H 16
#define DIM 64
#define NUM_P 16
#define PM 512            // P*M
#define ROWLEN 16384      // R*H*PM
#define APITCH 68         // padded anchor row pitch (floats), 16B-aligned, breaks bank aliasing

__global__ __launch_bounds__(256) void slay_features_kernel(
    const float* __restrict__ x,
    const float* __restrict__ omega,
    const float* __restrict__ anchors,
    float* __restrict__ out)
{
    __shared__ float shA[NUM_P * APITCH];   // anchors [p][d], padded pitch

    const int tid  = threadIdx.x;
    const int lane = tid & 63;
    const int wv   = tid >> 6;
    const int h    = blockIdx.x & 15;     // low bits: all h adjacent in dispatch order
    const int bg   = blockIdx.x >> 4;     // b-group of 8 rows

    // stage anchors [p][d] -> LDS [p][APITCH]
    for (int e = tid; e < NUM_P * DIM; e += 256) {
        const int p = e >> 6;
        const int d = e & 63;
        shA[p * APITCH + d] = anchors[e];
    }
    __syncthreads();

    // wave-uniform b0 (forced to SGPR so x loads become scalar loads)
    const int b0 = __builtin_amdgcn_readfirstlane(bg * 8 + wv * 2);

    const int r = lane >> 5;
    const int m = lane & 31;
    const int p = lane & 15;

    const float* xr0 = x + (size_t)b0 * 1024 + h * 64;          // uniform
    const float* xr1 = xr0 + 1024;                              // uniform
    const float* og  = omega + (size_t)r * 32768 + (size_t)h * 2048 + m;
    const float* ap  = shA + p * APITCH;

    float pr0 = 0.f, pr1 = 0.f, pl0 = 0.f, pl1 = 0.f, ss0 = 0.f, ss1 = 0.f;

    #pragma unroll
    for (int c = 0; c < 16; ++c) {
        const float4 xa = *(const float4*)(xr0 + c * 4);        // s_load_dwordx4
        const float4 xb = *(const float4*)(xr1 + c * 4);
        const float4 av = *(const float4*)(ap + c * 4);         // ds_read_b128, 2-way
        #pragma unroll
        for (int j = 0; j < 4; ++j) {
            const float xaj = (&xa.x)[j];
            const float xbj = (&xb.x)[j];
            const float avj = (&av.x)[j];
            const float w   = og[(size_t)(c * 4 + j) * 32];     // L1/L2-resident omega
            pr0 = fmaf(xaj, w,   pr0);
            pr1 = fmaf(xbj, w,   pr1);
            pl0 = fmaf(xaj, avj, pl0);
            pl1 = fmaf(xbj, avj, pl1);
            ss0 = fmaf(xaj, xaj, ss0);
            ss1 = fmaf(xbj, xbj, ss1);
        }
    }

    // normalization applied post-hoc: xn = x * inv  =>  dot(xn,.) = dot(x,.)*inv
    const float inv0 = 1.f / (sqrtf(fmaxf(ss0, 1e-12f)) + 1e-4f);
    const float inv1 = 1.f / (sqrtf(fmaxf(ss1, 1e-12f)) + 1e-4f);

    // ---- quadrature constants (match ref: float32(node) / C, then f32 math) ----
    const float S0 = (float)(0.5857864376269049 / 2.000001);
    const float S1 = (float)(3.4142135623730951 / 2.000001);
    const float Q0 = sqrtf(2.0f * S0);
    const float Q1 = sqrtf(2.0f * S1);
    const float K0 = sqrtf((float)(0.8535533905932737  / 2.000001) / 32.0f);
    const float K1 = sqrtf((float)(0.14644660940672624 / 2.000001) / 32.0f);
    const bool  hi = lane >= 32;
    const float sR = hi ? S1 : S0;
    const float qR = hi ? Q1 : Q0;
    const float kR = hi ? K1 : K0;

    // epilogue gather indices: lane writes float4 at idx = c*256 + lane*4 within a 512 block
    // p = c*8 + (lane>>3), m = (lane&7)*4 + j
    const int mb = (lane & 7) * 4;
    const int ps = lane >> 3;

    float* ob = out + (size_t)b0 * ROWLEN + h * PM;

    #pragma unroll
    for (int bb = 0; bb < 2; ++bb) {
        const float pr  = (bb ? pr1 : pr0) * (bb ? inv1 : inv0);
        const float pl  = (bb ? pl1 : pl0) * (bb ? inv1 : inv0);

        float arg = fmaf(pr, qR, -sR);
        arg = fminf(fmaxf(arg, -20.f), 20.f);
        const float prf = __expf(arg) * kR;      // lane's prf_feat(r=lane>>5, m=lane&31)
        const float pf  = pl * pl * 0.25f;       // lane's poly_feat(p=lane&15)

        const float p0  = __shfl(pf, ps);        // poly for c=0 chunk
        const float p1  = __shfl(pf, 8 + ps);    // poly for c=1 chunk
        const float q00 = __shfl(prf, mb + 0);   // r=0, m=mb..mb+3
        const float q01 = __shfl(prf, mb + 1);
        const float q02 = __shfl(prf, mb + 2);
        const float q03 = __shfl(prf, mb + 3);
        const float q10 = __shfl(prf, 32 + mb + 0); // r=1
        const float q11 = __shfl(prf, 32 + mb + 1);
        const float q12 = __shfl(prf, 32 + mb + 2);
        const float q13 = __shfl(prf, 32 + mb + 3);

        float* o = ob + (size_t)bb * ROWLEN;
        *(float4*)(o + lane * 4)              = make_float4(p0*q00, p0*q01, p0*q02, p0*q03); // r0,c0
        *(float4*)(o + 256 + lane * 4)        = make_float4(p1*q00, p1*q01, p1*q02, p1*q03); // r0,c1
        *(float4*)(o + 8192 + lane * 4)       = make_float4(p0*q10, p0*q11, p0*q12, p0*q13); // r1,c0
        *(float4*)(o + 8192 + 256 + lane * 4) = make_float4(p1*q10, p1*q11, p1*q12, p1*q13); // r1,c1
    }
}

extern "C" void kernel_launch(void* const* d_in, const int* in_sizes, int n_in,
                              void* d_out, int out_size, void* d_ws, size_t ws_size,
                              hipStream_t stream) {
    const float* x       = (const float*)d_in[0];
    const float* omega   = (const float*)d_in[1];
    const float* anchors = (const float*)d_in[2];
    float* out = (float*)d_out;

    const int B = in_sizes[0] / 1024;       // 8192
    dim3 grid((B / 8) * NUM_H);             // flat: h = bid & 15, b-group = bid >> 4
    dim3 block(256);
    slay_features_kernel<<<grid, block, 0, stream>>>(x, omega, anchors, out);
}

// Round 5
// 89.070 us; speedup vs baseline: 1.8644x; 1.2815x over previous
//
#include <hip/hip_runtime.h>
#include <hip/hip_bf16.h>

// SLAY features: B=8192, EMBED=1024, H=16, D=64, M=32, P=16, R=2
// out[b, r*8192 + h*512 + p*32 + m] = poly_feat[b,h,p] * prf_feat[r,b,h,m]
//
// One wave handles (h, b0, b0+1).
// R2: normalization folded post-hoc; x via scalar float4 loads; anchors via
//     ds_read_b128 from padded LDS. -> 114 us.
// R4: output stores NON-TEMPORAL via native ext_vector_type (HIP_vector_type
//     float4 is rejected by __builtin_nontemporal_store). Output is
//     write-once/never-read -> skip L2 allocation, stream to HBM.

#define NUM_H 16
#define DIM 64
#define NUM_P 16
#define PM 512            // P*M
#define ROWLEN 16384      // R*H*PM
#define APITCH 68         // padded anchor row pitch (floats)

typedef float f32x4 __attribute__((ext_vector_type(4)));

__global__ __launch_bounds__(256) void slay_features_kernel(
    const float* __restrict__ x,
    const float* __restrict__ omega,
    const float* __restrict__ anchors,
    float* __restrict__ out)
{
    __shared__ float shA[NUM_P * APITCH];   // anchors [p][d], padded pitch

    const int tid  = threadIdx.x;
    const int lane = tid & 63;
    const int wv   = tid >> 6;
    const int h    = blockIdx.x & 15;     // low bits: all h adjacent in dispatch order
    const int bg   = blockIdx.x >> 4;     // b-group of 8 rows

    // stage anchors [p][d] -> LDS [p][APITCH]
    for (int e = tid; e < NUM_P * DIM; e += 256) {
        const int p = e >> 6;
        const int d = e & 63;
        shA[p * APITCH + d] = anchors[e];
    }
    __syncthreads();

    // wave-uniform b0 (forced to SGPR so x loads become scalar loads)
    const int b0 = __builtin_amdgcn_readfirstlane(bg * 8 + wv * 2);

    const int r = lane >> 5;
    const int m = lane & 31;
    const int p = lane & 15;

    const float* xr0 = x + (size_t)b0 * 1024 + h * 64;          // uniform
    const float* xr1 = xr0 + 1024;                              // uniform
    const float* og  = omega + (size_t)r * 32768 + (size_t)h * 2048 + m;
    const float* ap  = shA + p * APITCH;

    float pr0 = 0.f, pr1 = 0.f, pl0 = 0.f, pl1 = 0.f, ss0 = 0.f, ss1 = 0.f;

    #pragma unroll
    for (int c = 0; c < 16; ++c) {
        const float4 xa = *(const float4*)(xr0 + c * 4);        // s_load_dwordx4
        const float4 xb = *(const float4*)(xr1 + c * 4);
        const float4 av = *(const float4*)(ap + c * 4);         // ds_read_b128, 2-way
        #pragma unroll
        for (int j = 0; j < 4; ++j) {
            const float xaj = (&xa.x)[j];
            const float xbj = (&xb.x)[j];
            const float avj = (&av.x)[j];
            const float w   = og[(size_t)(c * 4 + j) * 32];     // L1/L2-resident omega
            pr0 = fmaf(xaj, w,   pr0);
            pr1 = fmaf(xbj, w,   pr1);
            pl0 = fmaf(xaj, avj, pl0);
            pl1 = fmaf(xbj, avj, pl1);
            ss0 = fmaf(xaj, xaj, ss0);
            ss1 = fmaf(xbj, xbj, ss1);
        }
    }

    // normalization applied post-hoc: xn = x * inv  =>  dot(xn,.) = dot(x,.)*inv
    const float inv0 = 1.f / (sqrtf(fmaxf(ss0, 1e-12f)) + 1e-4f);
    const float inv1 = 1.f / (sqrtf(fmaxf(ss1, 1e-12f)) + 1e-4f);

    // ---- quadrature constants (match ref: float32(node) / C, then f32 math) ----
    const float S0 = (float)(0.5857864376269049 / 2.000001);
    const float S1 = (float)(3.4142135623730951 / 2.000001);
    const float Q0 = sqrtf(2.0f * S0);
    const float Q1 = sqrtf(2.0f * S1);
    const float K0 = sqrtf((float)(0.8535533905932737  / 2.000001) / 32.0f);
    const float K1 = sqrtf((float)(0.14644660940672624 / 2.000001) / 32.0f);
    const bool  hi = lane >= 32;
    const float sR = hi ? S1 : S0;
    const float qR = hi ? Q1 : Q0;
    const float kR = hi ? K1 : K0;

    // epilogue gather indices: lane writes float4 at idx = c*256 + lane*4 within a 512 block
    // p = c*8 + (lane>>3), m = (lane&7)*4 + j
    const int mb = (lane & 7) * 4;
    const int ps = lane >> 3;

    float* ob = out + (size_t)b0 * ROWLEN + h * PM;

    #pragma unroll
    for (int bb = 0; bb < 2; ++bb) {
        const float pr  = (bb ? pr1 : pr0) * (bb ? inv1 : inv0);
        const float pl  = (bb ? pl1 : pl0) * (bb ? inv1 : inv0);

        float arg = fmaf(pr, qR, -sR);
        arg = fminf(fmaxf(arg, -20.f), 20.f);
        const float prf = __expf(arg) * kR;      // lane's prf_feat(r=lane>>5, m=lane&31)
        const float pf  = pl * pl * 0.25f;       // lane's poly_feat(p=lane&15)

        const float p0  = __shfl(pf, ps);        // poly for c=0 chunk
        const float p1  = __shfl(pf, 8 + ps);    // poly for c=1 chunk
        const float q00 = __shfl(prf, mb + 0);   // r=0, m=mb..mb+3
        const float q01 = __shfl(prf, mb + 1);
        const float q02 = __shfl(prf, mb + 2);
        const float q03 = __shfl(prf, mb + 3);
        const float q10 = __shfl(prf, 32 + mb + 0); // r=1
        const float q11 = __shfl(prf, 32 + mb + 1);
        const float q12 = __shfl(prf, 32 + mb + 2);
        const float q13 = __shfl(prf, 32 + mb + 3);

        float* o = ob + (size_t)bb * ROWLEN;
        f32x4 v0 = {p0*q00, p0*q01, p0*q02, p0*q03};
        f32x4 v1 = {p1*q00, p1*q01, p1*q02, p1*q03};
        f32x4 v2 = {p0*q10, p0*q11, p0*q12, p0*q13};
        f32x4 v3 = {p1*q10, p1*q11, p1*q12, p1*q13};
        __builtin_nontemporal_store(v0, (f32x4*)(o + lane * 4));              // r0,c0
        __builtin_nontemporal_store(v1, (f32x4*)(o + 256 + lane * 4));        // r0,c1
        __builtin_nontemporal_store(v2, (f32x4*)(o + 8192 + lane * 4));       // r1,c0
        __builtin_nontemporal_store(v3, (f32x4*)(o + 8192 + 256 + lane * 4)); // r1,c1
    }
}

extern "C" void kernel_launch(void* const* d_in, const int* in_sizes, int n_in,
                              void* d_out, int out_size, void* d_ws, size_t ws_size,
                              hipStream_t stream) {
    const float* x       = (const float*)d_in[0];
    const float* omega   = (const float*)d_in[1];
    const float* anchors = (const float*)d_in[2];
    float* out = (float*)d_out;

    const int B = in_sizes[0] / 1024;       // 8192
    dim3 grid((B / 8) * NUM_H);             // flat: h = bid & 15, b-group = bid >> 4
    dim3 block(256);
    slay_features_kernel<<<grid, block, 0, stream>>>(x, omega, anchors, out);
}